// Round 3
// baseline (883.106 us; speedup 1.0000x reference)
//
#include <hip/hip_runtime.h>
#include <hip/hip_fp16.h>
#include <hip/hip_cooperative_groups.h>

namespace cg = cooperative_groups;

#define N_NODES 50000
#define N_EDGES 800000
#define D 64
#define NUM_GRAPHS 512
#define FINAL_NEURON 128
#define SCAN_NB ((N_NODES + 255) / 256)   // 196

#define BN 16                              // nodes per fused tile (50000/16 exact -> 3125)
#define NB_GEMM (N_NODES / BN)             // 3125
#define NB_EDGE (N_EDGES / 256)            // 3125 exact
#define ZS 72                              // LDS stride (halves)
#define WS 72
#define WELEM (D * WS)                     // 4608 halves per prepared W image

typedef unsigned short ushort_t;
typedef _Float16 f16;
typedef __attribute__((ext_vector_type(4))) _Float16 f16x4;
typedef __attribute__((ext_vector_type(8))) _Float16 f16x8;
typedef __attribute__((ext_vector_type(4))) float f32x4;

struct WPtrs { const float* w[5]; };

struct MegaArgs {
    const float* x;
    const int* src; const int* dst; const int* batch;
    const int* row; const ushort_t* epos; ushort_t* esrc;
    const float* dinv;
    const f16* whi[5]; const f16* wlo[5];
    const float* bias[5];
    __half* yA; __half* yB;
    float* g;
    const float* fc1W; const float* fc1b; const float* fc2W; const float* fc2b;
    float* out;
};

__device__ __forceinline__ float2 h2f(unsigned v) {
    __half2 h = *reinterpret_cast<__half2*>(&v);
    return __half22float2(h);
}

__device__ __forceinline__ void acc_add8(float4& a0, float4& a1, uint4 u) {
    float2 p;
    p = h2f(u.x); a0.x += p.x; a0.y += p.y;
    p = h2f(u.y); a0.z += p.x; a0.w += p.y;
    p = h2f(u.z); a1.x += p.x; a1.y += p.y;
    p = h2f(u.w); a1.z += p.x; a1.w += p.y;
}

// ---------------- CSR build + W hi/lo prep (unchanged, verified) -------------
__global__ void k_zero_prep(int* cnt, WPtrs wp, f16* __restrict__ whi, f16* __restrict__ wlo) {
    int b = blockIdx.x;
    if (b < SCAN_NB) {
        int i = b * 256 + threadIdx.x;
        if (i < N_NODES) cnt[i] = 0;
        return;
    }
    int l = b - SCAN_NB;                 // 0..4
    const float* W = wp.w[l];
    f16* hi = whi + l * WELEM;
    f16* lo = wlo + l * WELEM;
    for (int idx = threadIdx.x; idx < D * D; idx += 256) {
        int k = idx >> 6, j = idx & 63;
        float w = W[idx];
        f16 h = (f16)w;
        hi[j * WS + k] = h;
        lo[j * WS + k] = (f16)(w - (float)h);
    }
}

__global__ void k_hist(const int* __restrict__ dst, int* cnt, ushort_t* __restrict__ epos) {
    int e = blockIdx.x * blockDim.x + threadIdx.x;
    if (e < N_EDGES) epos[e] = (ushort_t)atomicAdd(&cnt[dst[e]], 1);
}

__global__ void k_blocksum(const int* __restrict__ cnt, int* __restrict__ bsum,
                           float* __restrict__ dinv, float* __restrict__ g) {
    __shared__ int sdata[256];
    int t = threadIdx.x;
    int i = blockIdx.x * 256 + t;
    int v = (i < N_NODES) ? cnt[i] : 0;
    if (i < N_NODES) dinv[i] = rsqrtf((float)v + 1.0f);
    if (i < NUM_GRAPHS * D) g[i] = 0.f;
    sdata[t] = v;
    __syncthreads();
    for (int s = 128; s > 0; s >>= 1) {
        if (t < s) sdata[t] += sdata[t + s];
        __syncthreads();
    }
    if (t == 0) bsum[blockIdx.x] = sdata[0];
}

__global__ void k_scanbsum(const int* __restrict__ bsum, int* __restrict__ boff) {
    __shared__ int buf[256];
    int t = threadIdx.x;
    int v = (t < SCAN_NB) ? bsum[t] : 0;
    buf[t] = v;
    __syncthreads();
    for (int off = 1; off < 256; off <<= 1) {
        int a = (t >= off) ? buf[t - off] : 0;
        __syncthreads();
        buf[t] += a;
        __syncthreads();
    }
    if (t < SCAN_NB) boff[t] = buf[t] - v;   // exclusive
}

__global__ void k_localscan(const int* __restrict__ cnt, const int* __restrict__ boff,
                            int* __restrict__ row) {
    __shared__ int buf[256];
    int t = threadIdx.x;
    int i = blockIdx.x * 256 + t;
    int v = (i < N_NODES) ? cnt[i] : 0;
    buf[t] = v;
    __syncthreads();
    for (int off = 1; off < 256; off <<= 1) {
        int a = (t >= off) ? buf[t - off] : 0;
        __syncthreads();
        buf[t] += a;
        __syncthreads();
    }
    if (i < N_NODES) row[i] = boff[blockIdx.x] + buf[t] - v;
    if (i == 0) row[N_NODES] = N_EDGES;
}

// ---------------- shared device pieces (unchanged, verified) -----------------
__device__ __forceinline__ void stage_w_lds(const f16* __restrict__ whi_g,
                                            const f16* __restrict__ wlo_g,
                                            f16* WhiT, f16* WloT, int t) {
    const uint4* sh = (const uint4*)whi_g;
    const uint4* sl = (const uint4*)wlo_g;
    uint4* dh = (uint4*)WhiT;
    uint4* dl = (uint4*)WloT;
#pragma unroll 3
    for (int i = 0; i < 3; ++i) {
        int idx = t + i * 256;
        if (idx < WELEM / 8) { dh[idx] = sh[idx]; dl[idx] = sl[idx]; }
    }
}

// Gather: 16 lanes per node (2 edge groups x 8 feature-chunks), stride-2 edge
// interleave, index stream prefetched one quad ahead (esrc padded).
__device__ __forceinline__ void gather_node16(const int* __restrict__ row,
                                              const ushort_t* __restrict__ esrc,
                                              const uint4* __restrict__ hp,
                                              int n, int g, int q, float4& a0, float4& a1) {
    int e = row[n] + g, e1 = row[n + 1];
    if (g == 0) acc_add8(a0, a1, hp[(size_t)n * 8 + q]);   // self-loop
    int i0 = __builtin_nontemporal_load(esrc + e);
    int i1 = __builtin_nontemporal_load(esrc + e + 2);
    int i2 = __builtin_nontemporal_load(esrc + e + 4);
    int i3 = __builtin_nontemporal_load(esrc + e + 6);
    while (e + 6 < e1) {
        uint4 u0 = hp[(size_t)i0 * 8 + q];
        uint4 u1 = hp[(size_t)i1 * 8 + q];
        uint4 u2 = hp[(size_t)i2 * 8 + q];
        uint4 u3 = hp[(size_t)i3 * 8 + q];
        e += 8;
        i0 = __builtin_nontemporal_load(esrc + e);
        i1 = __builtin_nontemporal_load(esrc + e + 2);
        i2 = __builtin_nontemporal_load(esrc + e + 4);
        i3 = __builtin_nontemporal_load(esrc + e + 6);
        acc_add8(a0, a1, u0); acc_add8(a0, a1, u1);
        acc_add8(a0, a1, u2); acc_add8(a0, a1, u3);
    }
    for (; e < e1; e += 2) {
        int s = __builtin_nontemporal_load(esrc + e);
        acc_add8(a0, a1, hp[(size_t)s * 8 + q]);
    }
}

// 16x64 @ 64x64 MFMA GEMM (4 waves, wave w owns cols w*16..+16), K=64 with
// hi/lo weight split. Scales rows by dinvsh, writes fp16 back into zsh.
__device__ __forceinline__ void gemm_16x64(f16* zsh, const f16* WhiT, const f16* WloT,
                                           const float* dinvsh, int t) {
    int w = t >> 6, l = t & 63;
    int cb = w * 16;
    int lr = l & 15, lg = l >> 4;
    f32x4 acc = {0.f, 0.f, 0.f, 0.f};
    f16x8 a0  = *(const f16x8*)&zsh[lr * ZS + lg * 8];
    f16x8 a1  = *(const f16x8*)&zsh[lr * ZS + 32 + lg * 8];
    f16x8 bh0 = *(const f16x8*)&WhiT[(cb + lr) * WS + lg * 8];
    f16x8 bl0 = *(const f16x8*)&WloT[(cb + lr) * WS + lg * 8];
    f16x8 bh1 = *(const f16x8*)&WhiT[(cb + lr) * WS + 32 + lg * 8];
    f16x8 bl1 = *(const f16x8*)&WloT[(cb + lr) * WS + 32 + lg * 8];
    acc = __builtin_amdgcn_mfma_f32_16x16x32_f16(a0, bh0, acc, 0, 0, 0);
    acc = __builtin_amdgcn_mfma_f32_16x16x32_f16(a0, bl0, acc, 0, 0, 0);
    acc = __builtin_amdgcn_mfma_f32_16x16x32_f16(a1, bh1, acc, 0, 0, 0);
    acc = __builtin_amdgcn_mfma_f32_16x16x32_f16(a1, bl1, acc, 0, 0, 0);
    __syncthreads();                 // all zsh reads done before overwrite
    // C/D layout: col = lane&15, row = (lane>>4)*4 + reg
#pragma unroll
    for (int r = 0; r < 4; ++r) {
        int rrow = lg * 4 + r;
        float s = dinvsh[rrow];
        zsh[rrow * ZS + cb + lr] = (f16)(acc[r] * s);
    }
}

// ---------------- mega kernel: transform+fill | 4 layers | layer5+pool | MLP -
__global__ __launch_bounds__(256, 6)
void k_mega(MegaArgs A) {
    cg::grid_group gridg = cg::this_grid();
    __shared__ __attribute__((aligned(16))) f16 WhiT[WELEM];
    __shared__ __attribute__((aligned(16))) f16 WloT[WELEM];
    __shared__ __attribute__((aligned(16))) f16 zsh[BN * ZS];
    __shared__ float dinvsh[BN];
    int t = threadIdx.x;
    const int nblk = gridDim.x;

    // ---- phase 0a: CSR edge fill (exact 3125 chunks of 256) ----
    for (int c = blockIdx.x; c < NB_EDGE; c += nblk) {
        int e = c * 256 + t;
        A.esrc[A.row[A.dst[e]] + (int)A.epos[e]] = (ushort_t)A.src[e];
    }
    // ---- phase 0b: y1 = dinv .* (x @ W1) ----
    stage_w_lds(A.whi[0], A.wlo[0], WhiT, WloT, t);
    __syncthreads();
    for (int tile = blockIdx.x; tile < NB_GEMM; tile += nblk) {
        int base = tile * BN;
        if (t < BN) dinvsh[t] = A.dinv[base + t];
        int nl = t >> 4, c4 = t & 15;
        float4 xv = ((const float4*)A.x)[(size_t)(base + nl) * 16 + c4];
        f16x4 zv = {(f16)xv.x, (f16)xv.y, (f16)xv.z, (f16)xv.w};
        *(f16x4*)&zsh[nl * ZS + c4 * 4] = zv;
        __syncthreads();
        gemm_16x64(zsh, WhiT, WloT, dinvsh, t);
        __syncthreads();
        if (t < 128) {
            int n2 = t >> 3, q = t & 7;
            uint4 o = *(const uint4*)&zsh[n2 * ZS + q * 8];
            ((uint4*)A.yA)[(size_t)(base + n2) * 8 + q] = o;
        }
        __syncthreads();
    }
    gridg.sync();

    // ---- layers 1..4: gather + bias/relu + (z @ Wnext)*dinv ----
    const __half* hin = A.yA;
    __half* hout = A.yB;
    for (int l = 0; l < 4; ++l) {
        stage_w_lds(A.whi[l + 1], A.wlo[l + 1], WhiT, WloT, t);
        __syncthreads();
        const float* bias = A.bias[l];
        for (int tile = blockIdx.x; tile < NB_GEMM; tile += nblk) {
            int base = tile * BN;
            if (t < BN) dinvsh[t] = A.dinv[base + t];
            int nl = t >> 4, m = t & 15, g = m >> 3, q = m & 7;
            int n = base + nl;
            float4 a0 = {0,0,0,0}, a1 = {0,0,0,0};
            gather_node16(A.row, A.esrc, (const uint4*)hin, n, g, q, a0, a1);
            a0.x += __shfl_xor(a0.x, 8); a0.y += __shfl_xor(a0.y, 8);
            a0.z += __shfl_xor(a0.z, 8); a0.w += __shfl_xor(a0.w, 8);
            a1.x += __shfl_xor(a1.x, 8); a1.y += __shfl_xor(a1.y, 8);
            a1.z += __shfl_xor(a1.z, 8); a1.w += __shfl_xor(a1.w, 8);
            float s = A.dinv[n];
            float4 b0 = ((const float4*)bias)[2 * q];
            float4 b1 = ((const float4*)bias)[2 * q + 1];
            if (g == 0) {
                f16x8 zv;
                zv[0] = (f16)fmaxf(a0.x * s + b0.x, 0.f);
                zv[1] = (f16)fmaxf(a0.y * s + b0.y, 0.f);
                zv[2] = (f16)fmaxf(a0.z * s + b0.z, 0.f);
                zv[3] = (f16)fmaxf(a0.w * s + b0.w, 0.f);
                zv[4] = (f16)fmaxf(a1.x * s + b1.x, 0.f);
                zv[5] = (f16)fmaxf(a1.y * s + b1.y, 0.f);
                zv[6] = (f16)fmaxf(a1.z * s + b1.z, 0.f);
                zv[7] = (f16)fmaxf(a1.w * s + b1.w, 0.f);
                *(f16x8*)&zsh[nl * ZS + q * 8] = zv;
            }
            __syncthreads();
            gemm_16x64(zsh, WhiT, WloT, dinvsh, t);
            __syncthreads();
            if (t < 128) {
                int n2 = t >> 3, q2 = t & 7;
                uint4 o = *(const uint4*)&zsh[n2 * ZS + q2 * 8];
                ((uint4*)hout)[(size_t)(base + n2) * 8 + q2] = o;
            }
            __syncthreads();
        }
        gridg.sync();
        __half* tmp = (__half*)hin; hin = hout; hout = tmp;
    }

    // ---- layer 5 + fused global_add_pool (hin == yA here) ----
    {
        float* zf = (float*)WhiT;            // 16*68*4 = 4352 B <= 9216 B
        int*   bsh = (int*)WloT;
        const float* bias = A.bias[4];
        for (int tile = blockIdx.x; tile < NB_GEMM; tile += nblk) {
            int base = tile * BN;
            if (t < BN) bsh[t] = A.batch[base + t];
            int nl = t >> 4, m = t & 15, g2 = m >> 3, q = m & 7;
            int n = base + nl;
            float4 a0 = {0,0,0,0}, a1 = {0,0,0,0};
            gather_node16(A.row, A.esrc, (const uint4*)hin, n, g2, q, a0, a1);
            a0.x += __shfl_xor(a0.x, 8); a0.y += __shfl_xor(a0.y, 8);
            a0.z += __shfl_xor(a0.z, 8); a0.w += __shfl_xor(a0.w, 8);
            a1.x += __shfl_xor(a1.x, 8); a1.y += __shfl_xor(a1.y, 8);
            a1.z += __shfl_xor(a1.z, 8); a1.w += __shfl_xor(a1.w, 8);
            float s = A.dinv[n];
            float4 b0 = ((const float4*)bias)[2 * q];
            float4 b1 = ((const float4*)bias)[2 * q + 1];
            if (g2 == 0) {
                float4 r0, r1;
                r0.x = fmaxf(a0.x * s + b0.x, 0.f);
                r0.y = fmaxf(a0.y * s + b0.y, 0.f);
                r0.z = fmaxf(a0.z * s + b0.z, 0.f);
                r0.w = fmaxf(a0.w * s + b0.w, 0.f);
                r1.x = fmaxf(a1.x * s + b1.x, 0.f);
                r1.y = fmaxf(a1.y * s + b1.y, 0.f);
                r1.z = fmaxf(a1.z * s + b1.z, 0.f);
                r1.w = fmaxf(a1.w * s + b1.w, 0.f);
                *(float4*)&zf[nl * 68 + q * 8]     = r0;
                *(float4*)&zf[nl * 68 + q * 8 + 4] = r1;
            }
            __syncthreads();
            int f = t & 63, grp = t >> 6;
            int n0 = grp * 4;
            int cur = bsh[n0];
            float acc = 0.f;
#pragma unroll
            for (int k2 = 0; k2 < 4; ++k2) {
                int bb = bsh[n0 + k2];
                if (bb != cur) { atomicAdd(&A.g[cur * D + f], acc); acc = 0.f; cur = bb; }
                acc += zf[(n0 + k2) * 68 + f];
            }
            atomicAdd(&A.g[cur * D + f], acc);
            __syncthreads();
        }
    }
    gridg.sync();

    // ---- MLP: blocks 0..511, one graph row each ----
    if (blockIdx.x < NUM_GRAPHS) {
        float* red = (float*)zsh;            // 128 floats <= 2304 B
        int rowi = blockIdx.x;
        float acc = 0.f;
        if (t < FINAL_NEURON) {
#pragma unroll
            for (int k = 0; k < D; ++k)
                acc += A.g[rowi * D + k] * A.fc1W[k * FINAL_NEURON + t];
            acc = fmaxf(acc + A.fc1b[t], 0.f);
            red[t] = acc * A.fc2W[t];
        }
        __syncthreads();
        for (int s = 64; s > 0; s >>= 1) {
            if (t < s) red[t] += red[t + s];
            __syncthreads();
        }
        if (t == 0) A.out[rowi] = red[0] + A.fc2b[0];
    }
}

extern "C" void kernel_launch(void* const* d_in, const int* in_sizes, int n_in,
                              void* d_out, int out_size, void* d_ws, size_t ws_size,
                              hipStream_t stream) {
    const float* x     = (const float*)d_in[0];
    const int*   ei    = (const int*)d_in[1];
    const int*   src   = ei;
    const int*   dst   = ei + N_EDGES;
    const int*   batch = (const int*)d_in[2];
    WPtrs wp;
    wp.w[0] = (const float*)d_in[3];  wp.w[1] = (const float*)d_in[5];
    wp.w[2] = (const float*)d_in[7];  wp.w[3] = (const float*)d_in[9];
    wp.w[4] = (const float*)d_in[11];
    const float* b[5]  = {(const float*)d_in[4], (const float*)d_in[6], (const float*)d_in[8],
                          (const float*)d_in[10], (const float*)d_in[12]};
    float* out = (float*)d_out;

    __half*   yA   = (__half*)d_ws;                      // [N][64] fp16
    __half*   yB   = yA + (size_t)N_NODES * D;           // [N][64] fp16
    f16*      whiG = (f16*)(yB + (size_t)N_NODES * D);   // 5 * WELEM
    f16*      wloG = whiG + 5 * WELEM;                   // 5 * WELEM
    float*    g    = (float*)(wloG + 5 * WELEM);         // G*D
    float*    dinv = g + NUM_GRAPHS * D;                 // N
    int*      cnt  = (int*)(dinv + N_NODES);             // N
    int*      row  = cnt + N_NODES;                      // N+1
    int*      bsum = row + N_NODES + 1;                  // 256
    int*      boff = bsum + 256;                         // 256
    ushort_t* epos = (ushort_t*)(boff + 256);            // E ushort
    ushort_t* esrc = epos + N_EDGES;                     // E ushort (+16 pad)

    // ---- CSR build + W prep (5 small kernels) ----
    k_zero_prep<<<SCAN_NB + 5, 256, 0, stream>>>(cnt, wp, whiG, wloG);
    k_hist<<<(N_EDGES + 255) / 256, 256, 0, stream>>>(dst, cnt, epos);
    k_blocksum<<<SCAN_NB, 256, 0, stream>>>(cnt, bsum, dinv, g);
    k_scanbsum<<<1, 256, 0, stream>>>(bsum, boff);
    k_localscan<<<SCAN_NB, 256, 0, stream>>>(cnt, boff, row);

    // ---- everything else: one cooperative kernel ----
    MegaArgs A;
    A.x = x; A.src = src; A.dst = dst; A.batch = batch;
    A.row = row; A.epos = epos; A.esrc = esrc; A.dinv = dinv;
    for (int l = 0; l < 5; ++l) {
        A.whi[l] = whiG + l * WELEM;
        A.wlo[l] = wloG + l * WELEM;
        A.bias[l] = b[l];
    }
    A.yA = yA; A.yB = yB; A.g = g;
    A.fc1W = (const float*)d_in[13]; A.fc1b = (const float*)d_in[14];
    A.fc2W = (const float*)d_in[15]; A.fc2b = (const float*)d_in[16];
    A.out = out;

    static int gblocks = 0;
    if (gblocks == 0) {
        int nb = 0;
        hipError_t err = hipOccupancyMaxActiveBlocksPerMultiprocessor(&nb, k_mega, 256, 0);
        if (err != hipSuccess || nb < 1) nb = 4;   // conservative fallback
        gblocks = nb * 256;                        // 256 CUs on MI355X
        if (gblocks > NB_GEMM) gblocks = NB_GEMM;
    }
    void* kp[] = { (void*)&A };
    hipLaunchCooperativeKernel(k_mega, dim3(gblocks), dim3(256), kp, 0, stream);
}

// Round 4
// 299.501 us; speedup vs baseline: 2.9486x; 2.9486x over previous
//
#include <hip/hip_runtime.h>
#include <hip/hip_fp16.h>

#define N_NODES 50000
#define N_EDGES 800000
#define D 64
#define NUM_GRAPHS 512
#define FINAL_NEURON 128
#define SCAN_NB ((N_NODES + 255) / 256)   // 196

#define BN 16                              // nodes per GEMM block (50000/16 exact)
#define NB_GEMM (N_NODES / BN)             // 3125
#define NB_EDGE (N_EDGES / 256)            // 3125 exact
#define BG 32                              // nodes per gather block
#define NB_GATH (((N_NODES + BG - 1) / BG) * 2)   // 2 parity phases
#define ZS 72                              // LDS stride (halves)
#define WS 72
#define WELEM (D * WS)                     // 4608 halves per prepared W image

// planar fp16 layout: plane p (0/1) holds features [32p, 32p+32) of all nodes
#define PLANE_U4 ((size_t)N_NODES * 4)     // uint4 units per plane (64B/node)

typedef unsigned short ushort_t;
typedef _Float16 f16;
typedef __attribute__((ext_vector_type(4))) _Float16 f16x4;
typedef __attribute__((ext_vector_type(8))) _Float16 f16x8;
typedef __attribute__((ext_vector_type(4))) float f32x4;

struct WPtrs { const float* w[5]; };

__device__ __forceinline__ float2 h2f(unsigned v) {
    __half2 h = *reinterpret_cast<__half2*>(&v);
    return __half22float2(h);
}

__device__ __forceinline__ void acc_add8(float4& a0, float4& a1, uint4 u) {
    float2 p;
    p = h2f(u.x); a0.x += p.x; a0.y += p.y;
    p = h2f(u.y); a0.z += p.x; a0.w += p.y;
    p = h2f(u.z); a1.x += p.x; a1.y += p.y;
    p = h2f(u.w); a1.z += p.x; a1.w += p.y;
}

// ---------------- CSR build + W hi/lo prep (verified) ----------------
__global__ void k_zero_prep(int* cnt, WPtrs wp, f16* __restrict__ whi, f16* __restrict__ wlo) {
    int b = blockIdx.x;
    if (b < SCAN_NB) {
        int i = b * 256 + threadIdx.x;
        if (i < N_NODES) cnt[i] = 0;
        return;
    }
    int l = b - SCAN_NB;                 // 0..4
    const float* W = wp.w[l];
    f16* hi = whi + l * WELEM;
    f16* lo = wlo + l * WELEM;
    for (int idx = threadIdx.x; idx < D * D; idx += 256) {
        int k = idx >> 6, j = idx & 63;
        float w = W[idx];
        f16 h = (f16)w;
        hi[j * WS + k] = h;
        lo[j * WS + k] = (f16)(w - (float)h);
    }
}

__global__ void k_hist(const int* __restrict__ dst, int* cnt, ushort_t* __restrict__ epos) {
    int e = blockIdx.x * blockDim.x + threadIdx.x;
    if (e < N_EDGES) epos[e] = (ushort_t)atomicAdd(&cnt[dst[e]], 1);
}

__global__ void k_blocksum(const int* __restrict__ cnt, int* __restrict__ bsum,
                           float* __restrict__ dinv, float* __restrict__ g) {
    __shared__ int sdata[256];
    int t = threadIdx.x;
    int i = blockIdx.x * 256 + t;
    int v = (i < N_NODES) ? cnt[i] : 0;
    if (i < N_NODES) dinv[i] = rsqrtf((float)v + 1.0f);
    if (i < NUM_GRAPHS * D) g[i] = 0.f;
    sdata[t] = v;
    __syncthreads();
    for (int s = 128; s > 0; s >>= 1) {
        if (t < s) sdata[t] += sdata[t + s];
        __syncthreads();
    }
    if (t == 0) bsum[blockIdx.x] = sdata[0];
}

__global__ void k_scanbsum(const int* __restrict__ bsum, int* __restrict__ boff) {
    __shared__ int buf[256];
    int t = threadIdx.x;
    int v = (t < SCAN_NB) ? bsum[t] : 0;
    buf[t] = v;
    __syncthreads();
    for (int off = 1; off < 256; off <<= 1) {
        int a = (t >= off) ? buf[t - off] : 0;
        __syncthreads();
        buf[t] += a;
        __syncthreads();
    }
    if (t < SCAN_NB) boff[t] = buf[t] - v;   // exclusive
}

__global__ void k_localscan(const int* __restrict__ cnt, const int* __restrict__ boff,
                            int* __restrict__ row) {
    __shared__ int buf[256];
    int t = threadIdx.x;
    int i = blockIdx.x * 256 + t;
    int v = (i < N_NODES) ? cnt[i] : 0;
    buf[t] = v;
    __syncthreads();
    for (int off = 1; off < 256; off <<= 1) {
        int a = (t >= off) ? buf[t - off] : 0;
        __syncthreads();
        buf[t] += a;
        __syncthreads();
    }
    if (i < N_NODES) row[i] = boff[blockIdx.x] + buf[t] - v;
    if (i == 0) row[N_NODES] = N_EDGES;
}

// ---------------- shared device pieces ----------------
__device__ __forceinline__ void stage_w_lds(const f16* __restrict__ whi_g,
                                            const f16* __restrict__ wlo_g,
                                            f16* WhiT, f16* WloT, int t) {
    const uint4* sh = (const uint4*)whi_g;
    const uint4* sl = (const uint4*)wlo_g;
    uint4* dh = (uint4*)WhiT;
    uint4* dl = (uint4*)WloT;
#pragma unroll 3
    for (int i = 0; i < 3; ++i) {
        int idx = t + i * 256;
        if (idx < WELEM / 8) { dh[idx] = sh[idx]; dl[idx] = sl[idx]; }
    }
}

// Planar gather core: 8 lanes per node = 2 edge-groups (stride-2) x 4 chunks
// (16B each, one 64B plane row per edge). Index stream prefetched one quad
// ahead (esrc padded by 16 entries).
__device__ __forceinline__ void gather_plane(const int* __restrict__ row,
                                             const ushort_t* __restrict__ esrc,
                                             const uint4* __restrict__ hp,
                                             int n, int grp, int q,
                                             float4& a0, float4& a1) {
    int e = row[n] + grp, e1 = row[n + 1];
    if (grp == 0) acc_add8(a0, a1, hp[(size_t)n * 4 + q]);   // self-loop
    int i0 = __builtin_nontemporal_load(esrc + e);
    int i1 = __builtin_nontemporal_load(esrc + e + 2);
    int i2 = __builtin_nontemporal_load(esrc + e + 4);
    int i3 = __builtin_nontemporal_load(esrc + e + 6);
    while (e + 6 < e1) {
        uint4 u0 = hp[(size_t)i0 * 4 + q];
        uint4 u1 = hp[(size_t)i1 * 4 + q];
        uint4 u2 = hp[(size_t)i2 * 4 + q];
        uint4 u3 = hp[(size_t)i3 * 4 + q];
        e += 8;
        i0 = __builtin_nontemporal_load(esrc + e);
        i1 = __builtin_nontemporal_load(esrc + e + 2);
        i2 = __builtin_nontemporal_load(esrc + e + 4);
        i3 = __builtin_nontemporal_load(esrc + e + 6);
        acc_add8(a0, a1, u0); acc_add8(a0, a1, u1);
        acc_add8(a0, a1, u2); acc_add8(a0, a1, u3);
    }
    for (; e < e1; e += 2) {
        int s = __builtin_nontemporal_load(esrc + e);
        acc_add8(a0, a1, hp[(size_t)s * 4 + q]);
    }
}

// 16x64 @ 64x64 MFMA GEMM (verified): 4 waves, wave w owns cols w*16..+16,
// K=64 with hi/lo weight split; scales rows by dinvsh, writes fp16 into zsh.
__device__ __forceinline__ void gemm_16x64(f16* zsh, const f16* WhiT, const f16* WloT,
                                           const float* dinvsh, int t) {
    int w = t >> 6, l = t & 63;
    int cb = w * 16;
    int lr = l & 15, lg = l >> 4;
    f32x4 acc = {0.f, 0.f, 0.f, 0.f};
    f16x8 a0  = *(const f16x8*)&zsh[lr * ZS + lg * 8];
    f16x8 a1  = *(const f16x8*)&zsh[lr * ZS + 32 + lg * 8];
    f16x8 bh0 = *(const f16x8*)&WhiT[(cb + lr) * WS + lg * 8];
    f16x8 bl0 = *(const f16x8*)&WloT[(cb + lr) * WS + lg * 8];
    f16x8 bh1 = *(const f16x8*)&WhiT[(cb + lr) * WS + 32 + lg * 8];
    f16x8 bl1 = *(const f16x8*)&WloT[(cb + lr) * WS + 32 + lg * 8];
    acc = __builtin_amdgcn_mfma_f32_16x16x32_f16(a0, bh0, acc, 0, 0, 0);
    acc = __builtin_amdgcn_mfma_f32_16x16x32_f16(a0, bl0, acc, 0, 0, 0);
    acc = __builtin_amdgcn_mfma_f32_16x16x32_f16(a1, bh1, acc, 0, 0, 0);
    acc = __builtin_amdgcn_mfma_f32_16x16x32_f16(a1, bl1, acc, 0, 0, 0);
    __syncthreads();                 // all zsh reads done before overwrite
    // C/D layout: col = lane&15, row = (lane>>4)*4 + reg
#pragma unroll
    for (int r = 0; r < 4; ++r) {
        int rrow = lg * 4 + r;
        float s = dinvsh[rrow];
        zsh[rrow * ZS + cb + lr] = (f16)(acc[r] * s);
    }
}

// ---------------- transform0: y1 = dinv .* (x @ W1) planar; + CSR fill -------
__global__ __launch_bounds__(256, 6)
void k_transform0(const float* __restrict__ x, const float* __restrict__ dinv,
                  const f16* __restrict__ whi_g, const f16* __restrict__ wlo_g,
                  __half* __restrict__ hout,
                  const int* __restrict__ src, const int* __restrict__ dst,
                  const int* __restrict__ row, const ushort_t* __restrict__ epos,
                  ushort_t* __restrict__ esrc) {
    int t = threadIdx.x;
    if (blockIdx.x >= NB_GEMM) {           // edge-fill blocks
        int e = (blockIdx.x - NB_GEMM) * 256 + t;
        if (e < N_EDGES) esrc[row[dst[e]] + (int)epos[e]] = (ushort_t)src[e];
        return;
    }
    __shared__ __attribute__((aligned(16))) f16 WhiT[WELEM];
    __shared__ __attribute__((aligned(16))) f16 WloT[WELEM];
    __shared__ __attribute__((aligned(16))) f16 zsh[BN * ZS];
    __shared__ float dinvsh[BN];
    int base = blockIdx.x * BN;
    stage_w_lds(whi_g, wlo_g, WhiT, WloT, t);
    if (t < BN) dinvsh[t] = dinv[base + t];

    int nl = t >> 4, c4 = t & 15;
    float4 xv = ((const float4*)x)[(size_t)(base + nl) * 16 + c4];
    f16x4 zv = {(f16)xv.x, (f16)xv.y, (f16)xv.z, (f16)xv.w};
    *(f16x4*)&zsh[nl * ZS + c4 * 4] = zv;
    __syncthreads();
    gemm_16x64(zsh, WhiT, WloT, dinvsh, t);
    __syncthreads();
    if (t < 128) {                     // planar store: chunk c -> plane c>>2
        int n2 = t >> 3, c = t & 7;
        uint4 o = *(const uint4*)&zsh[n2 * ZS + c * 8];
        ((uint4*)hout)[(size_t)(c >> 2) * PLANE_U4 + (size_t)(base + n2) * 4 + (c & 3)] = o;
    }
}

// ---------------- gather: agg_p = fp16(dinv .* (A+I) y_p), XCD-parity --------
// blockIdx&1 = plane; even blocks -> even XCDs stream plane0 (3.2MB < 4MB L2).
__global__ __launch_bounds__(256, 8)
void k_gatherp(const int* __restrict__ row, const ushort_t* __restrict__ esrc,
               const __half* __restrict__ hin, const float* __restrict__ dinv,
               __half* __restrict__ agg) {
    int t = threadIdx.x;
    int p = blockIdx.x & 1;
    int n = (blockIdx.x >> 1) * BG + (t >> 3);
    if (n >= N_NODES) return;
    int m = t & 7, grp = m >> 2, q = m & 3;
    const uint4* hp = (const uint4*)hin + (size_t)p * PLANE_U4;
    float4 a0 = {0,0,0,0}, a1 = {0,0,0,0};
    gather_plane(row, esrc, hp, n, grp, q, a0, a1);
    // merge the two edge-group partials (lane ^ 4 within the 8-lane node group)
    a0.x += __shfl_xor(a0.x, 4); a0.y += __shfl_xor(a0.y, 4);
    a0.z += __shfl_xor(a0.z, 4); a0.w += __shfl_xor(a0.w, 4);
    a1.x += __shfl_xor(a1.x, 4); a1.y += __shfl_xor(a1.y, 4);
    a1.z += __shfl_xor(a1.z, 4); a1.w += __shfl_xor(a1.w, 4);
    if (grp == 0) {
        float s = dinv[n];
        __half2 q0 = __floats2half2_rn(a0.x * s, a0.y * s);
        __half2 q1 = __floats2half2_rn(a0.z * s, a0.w * s);
        __half2 q2 = __floats2half2_rn(a1.x * s, a1.y * s);
        __half2 q3 = __floats2half2_rn(a1.z * s, a1.w * s);
        uint4 pk = {*(unsigned*)&q0, *(unsigned*)&q1, *(unsigned*)&q2, *(unsigned*)&q3};
        ((uint4*)agg)[(size_t)p * PLANE_U4 + (size_t)n * 4 + q] = pk;
    }
}

// ---------------- apply: y' = dinv .* (relu(agg + b) @ Wnext), planar --------
__global__ __launch_bounds__(256, 6)
void k_applyp(const __half* __restrict__ agg, const float* __restrict__ dinv,
              const float* __restrict__ bias,
              const f16* __restrict__ whi_g, const f16* __restrict__ wlo_g,
              __half* __restrict__ hout) {
    __shared__ __attribute__((aligned(16))) f16 WhiT[WELEM];
    __shared__ __attribute__((aligned(16))) f16 WloT[WELEM];
    __shared__ __attribute__((aligned(16))) f16 zsh[BN * ZS];
    __shared__ float dinvsh[BN];
    int t = threadIdx.x;
    int base = blockIdx.x * BN;
    stage_w_lds(whi_g, wlo_g, WhiT, WloT, t);
    if (t < BN) dinvsh[t] = dinv[base + t];
    if (t < 128) {                     // stage z = relu(agg + b) from planar
        int nl = t >> 3, c = t & 7;
        uint4 u = ((const uint4*)agg)[(size_t)(c >> 2) * PLANE_U4 +
                                      (size_t)(base + nl) * 4 + (c & 3)];
        float4 b0 = ((const float4*)bias)[2 * c];
        float4 b1 = ((const float4*)bias)[2 * c + 1];
        float2 pp;
        f16x8 zv;
        pp = h2f(u.x); zv[0] = (f16)fmaxf(pp.x + b0.x, 0.f); zv[1] = (f16)fmaxf(pp.y + b0.y, 0.f);
        pp = h2f(u.y); zv[2] = (f16)fmaxf(pp.x + b0.z, 0.f); zv[3] = (f16)fmaxf(pp.y + b0.w, 0.f);
        pp = h2f(u.z); zv[4] = (f16)fmaxf(pp.x + b1.x, 0.f); zv[5] = (f16)fmaxf(pp.y + b1.y, 0.f);
        pp = h2f(u.w); zv[6] = (f16)fmaxf(pp.x + b1.z, 0.f); zv[7] = (f16)fmaxf(pp.y + b1.w, 0.f);
        *(f16x8*)&zsh[nl * ZS + c * 8] = zv;
    }
    __syncthreads();
    gemm_16x64(zsh, WhiT, WloT, dinvsh, t);
    __syncthreads();
    if (t < 128) {                     // planar store
        int n2 = t >> 3, c = t & 7;
        uint4 o = *(const uint4*)&zsh[n2 * ZS + c * 8];
        ((uint4*)hout)[(size_t)(c >> 2) * PLANE_U4 + (size_t)(base + n2) * 4 + (c & 3)] = o;
    }
}

// ---------------- layer-5 gather + relu/bias + fused pool (per plane) --------
__global__ __launch_bounds__(256, 8)
void k_gather_pool(const int* __restrict__ row, const ushort_t* __restrict__ esrc,
                   const __half* __restrict__ hin, const float* __restrict__ dinv,
                   const float* __restrict__ bias, const int* __restrict__ batch,
                   float* __restrict__ g) {
    __shared__ float zf[BG][36];
    __shared__ int bsh[BG];
    int t = threadIdx.x;
    int p = blockIdx.x & 1;
    int base = (blockIdx.x >> 1) * BG;
    if (t < BG) bsh[t] = (base + t < N_NODES) ? batch[base + t] : -1;
    int nl = t >> 3, m = t & 7, grp = m >> 2, q = m & 3;
    int n = base + nl;
    float4 a0 = {0,0,0,0}, a1 = {0,0,0,0};
    float s = 0.f;
    if (n < N_NODES) {
        const uint4* hp = (const uint4*)hin + (size_t)p * PLANE_U4;
        gather_plane(row, esrc, hp, n, grp, q, a0, a1);
        s = dinv[n];
    }
    a0.x += __shfl_xor(a0.x, 4); a0.y += __shfl_xor(a0.y, 4);
    a0.z += __shfl_xor(a0.z, 4); a0.w += __shfl_xor(a0.w, 4);
    a1.x += __shfl_xor(a1.x, 4); a1.y += __shfl_xor(a1.y, 4);
    a1.z += __shfl_xor(a1.z, 4); a1.w += __shfl_xor(a1.w, 4);
    if (grp == 0) {
        float4 b0 = ((const float4*)bias)[p * 8 + 2 * q];
        float4 b1 = ((const float4*)bias)[p * 8 + 2 * q + 1];
        float* zr = &zf[nl][q * 8];
        zr[0] = fmaxf(a0.x * s + b0.x, 0.f);
        zr[1] = fmaxf(a0.y * s + b0.y, 0.f);
        zr[2] = fmaxf(a0.z * s + b0.z, 0.f);
        zr[3] = fmaxf(a0.w * s + b0.w, 0.f);
        zr[4] = fmaxf(a1.x * s + b1.x, 0.f);
        zr[5] = fmaxf(a1.y * s + b1.y, 0.f);
        zr[6] = fmaxf(a1.z * s + b1.z, 0.f);
        zr[7] = fmaxf(a1.w * s + b1.w, 0.f);
    }
    __syncthreads();
    // pool: 32 plane-feats x 8 groups of 4 nodes; batch sorted -> few atomics
    int f = t & 31, gg = t >> 5;
    int n0 = gg * 4;
    int cur = bsh[n0];
    float acc = 0.f;
#pragma unroll
    for (int k2 = 0; k2 < 4; ++k2) {
        int bb = bsh[n0 + k2];
        if (bb < 0) break;
        if (bb != cur) { atomicAdd(&g[cur * D + p * 32 + f], acc); acc = 0.f; cur = bb; }
        acc += zf[n0 + k2][f];
    }
    if (cur >= 0) atomicAdd(&g[cur * D + p * 32 + f], acc);
}

// ---------------- fused MLP ----------------
__global__ void k_mlp(const float* __restrict__ g, const float* __restrict__ W1,
                      const float* __restrict__ b1, const float* __restrict__ W2,
                      const float* __restrict__ b2, float* __restrict__ out) {
    __shared__ float red[FINAL_NEURON];
    int row = blockIdx.x;
    int j = threadIdx.x;
    float acc = 0.f;
#pragma unroll
    for (int k = 0; k < D; ++k) acc += g[row * D + k] * W1[k * FINAL_NEURON + j];
    acc = fmaxf(acc + b1[j], 0.f);
    red[j] = acc * W2[j];
    __syncthreads();
    for (int s = 64; s > 0; s >>= 1) {
        if (j < s) red[j] += red[j + s];
        __syncthreads();
    }
    if (j == 0) out[row] = red[0] + b2[0];
}

extern "C" void kernel_launch(void* const* d_in, const int* in_sizes, int n_in,
                              void* d_out, int out_size, void* d_ws, size_t ws_size,
                              hipStream_t stream) {
    const float* x     = (const float*)d_in[0];
    const int*   ei    = (const int*)d_in[1];
    const int*   src   = ei;
    const int*   dst   = ei + N_EDGES;
    const int*   batch = (const int*)d_in[2];
    WPtrs wp;
    wp.w[0] = (const float*)d_in[3];  wp.w[1] = (const float*)d_in[5];
    wp.w[2] = (const float*)d_in[7];  wp.w[3] = (const float*)d_in[9];
    wp.w[4] = (const float*)d_in[11];
    const float* b[5]  = {(const float*)d_in[4], (const float*)d_in[6], (const float*)d_in[8],
                          (const float*)d_in[10], (const float*)d_in[12]};
    const float* fc1W  = (const float*)d_in[13];
    const float* fc1b  = (const float*)d_in[14];
    const float* fc2W  = (const float*)d_in[15];
    const float* fc2b  = (const float*)d_in[16];
    float* out = (float*)d_out;

    __half*   yA   = (__half*)d_ws;                      // [2][N][32] fp16 planar
    __half*   yB   = yA + (size_t)N_NODES * D;           // planar
    __half*   agg  = yB + (size_t)N_NODES * D;           // planar
    f16*      whiG = (f16*)(agg + (size_t)N_NODES * D);  // 5 * WELEM
    f16*      wloG = whiG + 5 * WELEM;                   // 5 * WELEM
    float*    g    = (float*)(wloG + 5 * WELEM);         // G*D
    float*    dinv = g + NUM_GRAPHS * D;                 // N
    int*      cnt  = (int*)(dinv + N_NODES);             // N
    int*      row  = cnt + N_NODES;                      // N+1
    int*      bsum = row + N_NODES + 1;                  // 256
    int*      boff = bsum + 256;                         // 256
    ushort_t* epos = (ushort_t*)(boff + 256);            // E ushort
    ushort_t* esrc = epos + N_EDGES;                     // E ushort (+16 pad)

    // ---- CSR build + W prep ----
    k_zero_prep<<<SCAN_NB + 5, 256, 0, stream>>>(cnt, wp, whiG, wloG);
    k_hist<<<(N_EDGES + 255) / 256, 256, 0, stream>>>(dst, cnt, epos);
    k_blocksum<<<SCAN_NB, 256, 0, stream>>>(cnt, bsum, dinv, g);
    k_scanbsum<<<1, 256, 0, stream>>>(bsum, boff);
    k_localscan<<<SCAN_NB, 256, 0, stream>>>(cnt, boff, row);

    // ---- y1 = dinv*(x@W1) planar + CSR fill ----
    k_transform0<<<NB_GEMM + NB_EDGE, 256, 0, stream>>>(x, dinv, whiG, wloG, yA,
                                                        src, dst, row, epos, esrc);

    // ---- 4 x (planar parity gather + MFMA apply) ----
    k_gatherp<<<NB_GATH, 256, 0, stream>>>(row, esrc, yA, dinv, agg);
    k_applyp <<<NB_GEMM, 256, 0, stream>>>(agg, dinv, b[0],
                                           whiG + 1 * WELEM, wloG + 1 * WELEM, yB);
    k_gatherp<<<NB_GATH, 256, 0, stream>>>(row, esrc, yB, dinv, agg);
    k_applyp <<<NB_GEMM, 256, 0, stream>>>(agg, dinv, b[1],
                                           whiG + 2 * WELEM, wloG + 2 * WELEM, yA);
    k_gatherp<<<NB_GATH, 256, 0, stream>>>(row, esrc, yA, dinv, agg);
    k_applyp <<<NB_GEMM, 256, 0, stream>>>(agg, dinv, b[2],
                                           whiG + 3 * WELEM, wloG + 3 * WELEM, yB);
    k_gatherp<<<NB_GATH, 256, 0, stream>>>(row, esrc, yB, dinv, agg);
    k_applyp <<<NB_GEMM, 256, 0, stream>>>(agg, dinv, b[3],
                                           whiG + 4 * WELEM, wloG + 4 * WELEM, yA);

    // ---- layer 5 gather + relu/bias + fused global_add_pool ----
    k_gather_pool<<<NB_GATH, 256, 0, stream>>>(row, esrc, yA, dinv, b[4], batch, g);

    // ---- MLP ----
    k_mlp<<<NUM_GRAPHS, FINAL_NEURON, 0, stream>>>(g, fc1W, fc1b, fc2W, fc2b, out);
}

// Round 5
// 242.560 us; speedup vs baseline: 3.6408x; 1.2348x over previous
//
#include <hip/hip_runtime.h>
#include <hip/hip_fp16.h>

#define N_NODES 50000
#define N_EDGES 800000
#define D 64
#define NUM_GRAPHS 512
#define FINAL_NEURON 128
#define SCAN_NB ((N_NODES + 255) / 256)   // 196

#define BN 16                              // nodes per GEMM block (50000/16 exact)
#define NB_GEMM (N_NODES / BN)             // 3125
#define NB_EDGE (N_EDGES / 256)            // 3125 exact
#define ZS 72                              // LDS stride (halves)
#define WS 72
#define WELEM (D * WS)                     // 4608 halves per prepared W image

typedef unsigned short ushort_t;
typedef _Float16 f16;
typedef __attribute__((ext_vector_type(4))) _Float16 f16x4;
typedef __attribute__((ext_vector_type(8))) _Float16 f16x8;
typedef __attribute__((ext_vector_type(4))) float f32x4;

struct WPtrs { const float* w[5]; };

__device__ __forceinline__ float2 h2f(unsigned v) {
    __half2 h = *reinterpret_cast<__half2*>(&v);
    return __half22float2(h);
}

__device__ __forceinline__ void acc_add8(float4& a0, float4& a1, uint4 u) {
    float2 p;
    p = h2f(u.x); a0.x += p.x; a0.y += p.y;
    p = h2f(u.y); a0.z += p.x; a0.w += p.y;
    p = h2f(u.z); a1.x += p.x; a1.y += p.y;
    p = h2f(u.w); a1.z += p.x; a1.w += p.y;
}

// ---------------- CSR build + W hi/lo prep (verified) ----------------
__global__ void k_zero_prep(int* cnt, WPtrs wp, f16* __restrict__ whi, f16* __restrict__ wlo) {
    int b = blockIdx.x;
    if (b < SCAN_NB) {
        int i = b * 256 + threadIdx.x;
        if (i < N_NODES) cnt[i] = 0;
        return;
    }
    int l = b - SCAN_NB;                 // 0..4
    const float* W = wp.w[l];
    f16* hi = whi + l * WELEM;
    f16* lo = wlo + l * WELEM;
    for (int idx = threadIdx.x; idx < D * D; idx += 256) {
        int k = idx >> 6, j = idx & 63;
        float w = W[idx];
        f16 h = (f16)w;
        hi[j * WS + k] = h;
        lo[j * WS + k] = (f16)(w - (float)h);
    }
}

__global__ void k_hist(const int* __restrict__ dst, int* cnt, ushort_t* __restrict__ epos) {
    int e = blockIdx.x * blockDim.x + threadIdx.x;
    if (e < N_EDGES) epos[e] = (ushort_t)atomicAdd(&cnt[dst[e]], 1);
}

__global__ void k_blocksum(const int* __restrict__ cnt, int* __restrict__ bsum,
                           float* __restrict__ dinv, float* __restrict__ g) {
    __shared__ int sdata[256];
    int t = threadIdx.x;
    int i = blockIdx.x * 256 + t;
    int v = (i < N_NODES) ? cnt[i] : 0;
    if (i < N_NODES) dinv[i] = rsqrtf((float)v + 1.0f);
    if (i < NUM_GRAPHS * D) g[i] = 0.f;
    sdata[t] = v;
    __syncthreads();
    for (int s = 128; s > 0; s >>= 1) {
        if (t < s) sdata[t] += sdata[t + s];
        __syncthreads();
    }
    if (t == 0) bsum[blockIdx.x] = sdata[0];
}

__global__ void k_scanbsum(const int* __restrict__ bsum, int* __restrict__ boff) {
    __shared__ int buf[256];
    int t = threadIdx.x;
    int v = (t < SCAN_NB) ? bsum[t] : 0;
    buf[t] = v;
    __syncthreads();
    for (int off = 1; off < 256; off <<= 1) {
        int a = (t >= off) ? buf[t - off] : 0;
        __syncthreads();
        buf[t] += a;
        __syncthreads();
    }
    if (t < SCAN_NB) boff[t] = buf[t] - v;   // exclusive
}

__global__ void k_localscan(const int* __restrict__ cnt, const int* __restrict__ boff,
                            int* __restrict__ row) {
    __shared__ int buf[256];
    int t = threadIdx.x;
    int i = blockIdx.x * 256 + t;
    int v = (i < N_NODES) ? cnt[i] : 0;
    buf[t] = v;
    __syncthreads();
    for (int off = 1; off < 256; off <<= 1) {
        int a = (t >= off) ? buf[t - off] : 0;
        __syncthreads();
        buf[t] += a;
        __syncthreads();
    }
    if (i < N_NODES) row[i] = boff[blockIdx.x] + buf[t] - v;
    if (i == 0) row[N_NODES] = N_EDGES;
}

// ---------------- gather: contiguous-half split, 8-wide latency rounds -------
// 16 lanes per node = 2 contiguous edge-halves x 8 feature-chunks (16B each).
// Per round: 8 independent index loads already in regs -> 8 independent data
// loads -> prefetch next 8 indices (overread <=8 past group end: esrc padded)
// -> accumulate. Serialized latency ~= L_idx + rounds*L_data.
__device__ __forceinline__ void gather_half(const int* __restrict__ row,
                                            const ushort_t* __restrict__ esrc,
                                            const uint4* __restrict__ hp,
                                            int n, int g, int q,
                                            float4& a0, float4& a1) {
    int e0 = row[n], e1 = row[n + 1];
    int len = e1 - e0;
    int h0 = (len + 1) >> 1;
    int e  = g ? (e0 + h0) : e0;
    int eg = g ? e1 : (e0 + h0);
    if (g) acc_add8(a0, a1, hp[(size_t)n * 8 + q]);   // self-loop (shorter half)
    int m = eg - e;
    int i0, i1, i2, i3, i4, i5, i6, i7;
    if (m >= 8) {
        i0 = esrc[e];     i1 = esrc[e + 1]; i2 = esrc[e + 2]; i3 = esrc[e + 3];
        i4 = esrc[e + 4]; i5 = esrc[e + 5]; i6 = esrc[e + 6]; i7 = esrc[e + 7];
        for (;;) {
            uint4 u0 = hp[(size_t)i0 * 8 + q], u1 = hp[(size_t)i1 * 8 + q];
            uint4 u2 = hp[(size_t)i2 * 8 + q], u3 = hp[(size_t)i3 * 8 + q];
            uint4 u4 = hp[(size_t)i4 * 8 + q], u5 = hp[(size_t)i5 * 8 + q];
            uint4 u6 = hp[(size_t)i6 * 8 + q], u7 = hp[(size_t)i7 * 8 + q];
            e += 8; m -= 8;
            i0 = esrc[e];     i1 = esrc[e + 1]; i2 = esrc[e + 2]; i3 = esrc[e + 3];
            i4 = esrc[e + 4]; i5 = esrc[e + 5]; i6 = esrc[e + 6]; i7 = esrc[e + 7];
            acc_add8(a0, a1, u0); acc_add8(a0, a1, u1);
            acc_add8(a0, a1, u2); acc_add8(a0, a1, u3);
            acc_add8(a0, a1, u4); acc_add8(a0, a1, u5);
            acc_add8(a0, a1, u6); acc_add8(a0, a1, u7);
            if (m < 8) break;
        }
        // i0..i7 hold the next 8 prefetched entries; first m are valid tail
    } else {
        if (m <= 0) return;
        i0 = esrc[e];     i1 = esrc[e + 1]; i2 = esrc[e + 2]; i3 = esrc[e + 3];
        i4 = esrc[e + 4]; i5 = esrc[e + 5]; i6 = esrc[e + 6]; i7 = esrc[e + 7];
    }
    if (m & 4) {
        uint4 u0 = hp[(size_t)i0 * 8 + q], u1 = hp[(size_t)i1 * 8 + q];
        uint4 u2 = hp[(size_t)i2 * 8 + q], u3 = hp[(size_t)i3 * 8 + q];
        acc_add8(a0, a1, u0); acc_add8(a0, a1, u1);
        acc_add8(a0, a1, u2); acc_add8(a0, a1, u3);
        i0 = i4; i1 = i5; i2 = i6; i3 = i7;
    }
    if (m & 2) {
        uint4 u0 = hp[(size_t)i0 * 8 + q], u1 = hp[(size_t)i1 * 8 + q];
        acc_add8(a0, a1, u0); acc_add8(a0, a1, u1);
        i0 = i2; i1 = i3;
    }
    if (m & 1) {
        uint4 u0 = hp[(size_t)i0 * 8 + q];
        acc_add8(a0, a1, u0);
    }
}

// ---------------- 16x64 @ 64x64 MFMA GEMM, W from global into registers ------
// Same fragment addressing as the verified LDS version; wave w owns cols
// w*16..+16. B-frags (hi/lo, 2 K-steps) are uniform per wave -> L2-hot.
__device__ __forceinline__ void gemm_16x64_reg(f16* zsh,
                                               const f16* __restrict__ whi_g,
                                               const f16* __restrict__ wlo_g,
                                               const float* dinvsh, int t) {
    int w = t >> 6, l = t & 63;
    int cb = w * 16;
    int lr = l & 15, lg = l >> 4;
    const f16* bhp = &whi_g[(cb + lr) * WS + lg * 8];
    const f16* blp = &wlo_g[(cb + lr) * WS + lg * 8];
    f16x8 bh0 = *(const f16x8*)bhp;
    f16x8 bl0 = *(const f16x8*)blp;
    f16x8 bh1 = *(const f16x8*)(bhp + 32);
    f16x8 bl1 = *(const f16x8*)(blp + 32);
    f32x4 acc = {0.f, 0.f, 0.f, 0.f};
    f16x8 a0 = *(const f16x8*)&zsh[lr * ZS + lg * 8];
    f16x8 a1 = *(const f16x8*)&zsh[lr * ZS + 32 + lg * 8];
    acc = __builtin_amdgcn_mfma_f32_16x16x32_f16(a0, bh0, acc, 0, 0, 0);
    acc = __builtin_amdgcn_mfma_f32_16x16x32_f16(a0, bl0, acc, 0, 0, 0);
    acc = __builtin_amdgcn_mfma_f32_16x16x32_f16(a1, bh1, acc, 0, 0, 0);
    acc = __builtin_amdgcn_mfma_f32_16x16x32_f16(a1, bl1, acc, 0, 0, 0);
    __syncthreads();                 // all zsh reads done before overwrite
    // C/D layout: col = lane&15, row = (lane>>4)*4 + reg
#pragma unroll
    for (int r = 0; r < 4; ++r) {
        int rrow = lg * 4 + r;
        float s = dinvsh[rrow];
        zsh[rrow * ZS + cb + lr] = (f16)(acc[r] * s);
    }
}

// ---------------- transform0: y1 = dinv .* (x @ W1), fp16; + CSR edge fill ---
__global__ __launch_bounds__(256, 8)
void k_transform0(const float* __restrict__ x, const float* __restrict__ dinv,
                  const f16* __restrict__ whi_g, const f16* __restrict__ wlo_g,
                  __half* __restrict__ hout,
                  const int* __restrict__ src, const int* __restrict__ dst,
                  const int* __restrict__ row, const ushort_t* __restrict__ epos,
                  ushort_t* __restrict__ esrc) {
    int t = threadIdx.x;
    if (blockIdx.x >= NB_GEMM) {           // edge-fill blocks
        int e = (blockIdx.x - NB_GEMM) * 256 + t;
        if (e < N_EDGES) esrc[row[dst[e]] + (int)epos[e]] = (ushort_t)src[e];
        return;
    }
    __shared__ __attribute__((aligned(16))) f16 zsh[BN * ZS];
    __shared__ float dinvsh[BN];
    int base = blockIdx.x * BN;
    if (t < BN) dinvsh[t] = dinv[base + t];

    int nl = t >> 4, c4 = t & 15;
    float4 xv = ((const float4*)x)[(size_t)(base + nl) * 16 + c4];
    f16x4 zv = {(f16)xv.x, (f16)xv.y, (f16)xv.z, (f16)xv.w};
    *(f16x4*)&zsh[nl * ZS + c4 * 4] = zv;
    __syncthreads();
    gemm_16x64_reg(zsh, whi_g, wlo_g, dinvsh, t);
    __syncthreads();
    if (t < 128) {
        int n2 = t >> 3, q = t & 7;
        uint4 o = *(const uint4*)&zsh[n2 * ZS + q * 8];
        ((uint4*)hout)[(size_t)(base + n2) * 8 + q] = o;
    }
}

// ---------------- fused layer: gather + relu/bias + (z @ Wnext)*dinv ---------
__global__ __launch_bounds__(256, 7)
void k_layer(const int* __restrict__ row, const ushort_t* __restrict__ esrc,
             const __half* __restrict__ hin, const float* __restrict__ dinv,
             const float* __restrict__ bias,
             const f16* __restrict__ whi_g, const f16* __restrict__ wlo_g,
             __half* __restrict__ hout) {
    __shared__ __attribute__((aligned(16))) f16 zsh[BN * ZS];
    __shared__ float dinvsh[BN];
    int t = threadIdx.x;
    int base = blockIdx.x * BN;
    if (t < BN) dinvsh[t] = dinv[base + t];

    int nl = t >> 4, m = t & 15, g = m >> 3, q = m & 7;
    int n = base + nl;
    float4 a0 = {0,0,0,0}, a1 = {0,0,0,0};
    gather_half(row, esrc, (const uint4*)hin, n, g, q, a0, a1);
    // merge the two edge-half partials
    a0.x += __shfl_xor(a0.x, 8); a0.y += __shfl_xor(a0.y, 8);
    a0.z += __shfl_xor(a0.z, 8); a0.w += __shfl_xor(a0.w, 8);
    a1.x += __shfl_xor(a1.x, 8); a1.y += __shfl_xor(a1.y, 8);
    a1.z += __shfl_xor(a1.z, 8); a1.w += __shfl_xor(a1.w, 8);
    float s = dinv[n];
    float4 b0 = ((const float4*)bias)[2 * q];
    float4 b1 = ((const float4*)bias)[2 * q + 1];
    if (g == 0) {
        f16x8 zv;
        zv[0] = (f16)fmaxf(a0.x * s + b0.x, 0.f);
        zv[1] = (f16)fmaxf(a0.y * s + b0.y, 0.f);
        zv[2] = (f16)fmaxf(a0.z * s + b0.z, 0.f);
        zv[3] = (f16)fmaxf(a0.w * s + b0.w, 0.f);
        zv[4] = (f16)fmaxf(a1.x * s + b1.x, 0.f);
        zv[5] = (f16)fmaxf(a1.y * s + b1.y, 0.f);
        zv[6] = (f16)fmaxf(a1.z * s + b1.z, 0.f);
        zv[7] = (f16)fmaxf(a1.w * s + b1.w, 0.f);
        *(f16x8*)&zsh[nl * ZS + q * 8] = zv;
    }
    __syncthreads();
    gemm_16x64_reg(zsh, whi_g, wlo_g, dinvsh, t);
    __syncthreads();
    if (t < 128) {
        int n2 = t >> 3, q2 = t & 7;
        uint4 o = *(const uint4*)&zsh[n2 * ZS + q2 * 8];
        ((uint4*)hout)[(size_t)(base + n2) * 8 + q2] = o;
    }
}

// ---------------- final layer: gather + relu/bias + fused global_add_pool ----
__global__ __launch_bounds__(256, 7)
void k_layer_pool(const int* __restrict__ row, const ushort_t* __restrict__ esrc,
                  const __half* __restrict__ hin, const float* __restrict__ dinv,
                  const float* __restrict__ bias, const int* __restrict__ batch,
                  float* __restrict__ g) {
    __shared__ float zf[BN * 68];
    __shared__ int bsh[BN];
    int t = threadIdx.x;
    int base = blockIdx.x * BN;
    if (t < BN) bsh[t] = batch[base + t];

    int nl = t >> 4, m = t & 15, g2 = m >> 3, q = m & 7;
    int n = base + nl;
    float4 a0 = {0,0,0,0}, a1 = {0,0,0,0};
    gather_half(row, esrc, (const uint4*)hin, n, g2, q, a0, a1);
    a0.x += __shfl_xor(a0.x, 8); a0.y += __shfl_xor(a0.y, 8);
    a0.z += __shfl_xor(a0.z, 8); a0.w += __shfl_xor(a0.w, 8);
    a1.x += __shfl_xor(a1.x, 8); a1.y += __shfl_xor(a1.y, 8);
    a1.z += __shfl_xor(a1.z, 8); a1.w += __shfl_xor(a1.w, 8);
    float s = dinv[n];
    float4 b0 = ((const float4*)bias)[2 * q];
    float4 b1 = ((const float4*)bias)[2 * q + 1];
    if (g2 == 0) {
        float4 r0, r1;
        r0.x = fmaxf(a0.x * s + b0.x, 0.f);
        r0.y = fmaxf(a0.y * s + b0.y, 0.f);
        r0.z = fmaxf(a0.z * s + b0.z, 0.f);
        r0.w = fmaxf(a0.w * s + b0.w, 0.f);
        r1.x = fmaxf(a1.x * s + b1.x, 0.f);
        r1.y = fmaxf(a1.y * s + b1.y, 0.f);
        r1.z = fmaxf(a1.z * s + b1.z, 0.f);
        r1.w = fmaxf(a1.w * s + b1.w, 0.f);
        *(float4*)&zf[nl * 68 + q * 8]     = r0;
        *(float4*)&zf[nl * 68 + q * 8 + 4] = r1;
    }
    __syncthreads();
    // pool: 4 groups x 4 nodes, 64 feats; batch sorted -> few boundary atomics
    int f = t & 63, grp = t >> 6;
    int n0 = grp * 4;
    int cur = bsh[n0];
    float acc = 0.f;
#pragma unroll
    for (int k2 = 0; k2 < 4; ++k2) {
        int bb = bsh[n0 + k2];
        if (bb != cur) { atomicAdd(&g[cur * D + f], acc); acc = 0.f; cur = bb; }
        acc += zf[(n0 + k2) * 68 + f];
    }
    atomicAdd(&g[cur * D + f], acc);
}

// ---------------- fused MLP ----------------
__global__ void k_mlp(const float* __restrict__ g, const float* __restrict__ W1,
                      const float* __restrict__ b1, const float* __restrict__ W2,
                      const float* __restrict__ b2, float* __restrict__ out) {
    __shared__ float red[FINAL_NEURON];
    int row = blockIdx.x;
    int j = threadIdx.x;
    float acc = 0.f;
#pragma unroll
    for (int k = 0; k < D; ++k) acc += g[row * D + k] * W1[k * FINAL_NEURON + j];
    acc = fmaxf(acc + b1[j], 0.f);
    red[j] = acc * W2[j];
    __syncthreads();
    for (int s = 64; s > 0; s >>= 1) {
        if (j < s) red[j] += red[j + s];
        __syncthreads();
    }
    if (j == 0) out[row] = red[0] + b2[0];
}

extern "C" void kernel_launch(void* const* d_in, const int* in_sizes, int n_in,
                              void* d_out, int out_size, void* d_ws, size_t ws_size,
                              hipStream_t stream) {
    const float* x     = (const float*)d_in[0];
    const int*   ei    = (const int*)d_in[1];
    const int*   src   = ei;
    const int*   dst   = ei + N_EDGES;
    const int*   batch = (const int*)d_in[2];
    WPtrs wp;
    wp.w[0] = (const float*)d_in[3];  wp.w[1] = (const float*)d_in[5];
    wp.w[2] = (const float*)d_in[7];  wp.w[3] = (const float*)d_in[9];
    wp.w[4] = (const float*)d_in[11];
    const float* b[5]  = {(const float*)d_in[4], (const float*)d_in[6], (const float*)d_in[8],
                          (const float*)d_in[10], (const float*)d_in[12]};
    const float* fc1W  = (const float*)d_in[13];
    const float* fc1b  = (const float*)d_in[14];
    const float* fc2W  = (const float*)d_in[15];
    const float* fc2b  = (const float*)d_in[16];
    float* out = (float*)d_out;

    __half*   yA   = (__half*)d_ws;                      // [N][64] fp16
    __half*   yB   = yA + (size_t)N_NODES * D;           // [N][64] fp16
    f16*      whiG = (f16*)(yB + (size_t)N_NODES * D);   // 5 * WELEM
    f16*      wloG = whiG + 5 * WELEM;                   // 5 * WELEM
    float*    g    = (float*)(wloG + 5 * WELEM);         // G*D
    float*    dinv = g + NUM_GRAPHS * D;                 // N
    int*      cnt  = (int*)(dinv + N_NODES);             // N
    int*      row  = cnt + N_NODES;                      // N+1
    int*      bsum = row + N_NODES + 1;                  // 256
    int*      boff = bsum + 256;                         // 256
    ushort_t* epos = (ushort_t*)(boff + 256);            // E ushort
    ushort_t* esrc = epos + N_EDGES;                     // E ushort (+pad: ws is larger)

    // ---- CSR build + W prep ----
    k_zero_prep<<<SCAN_NB + 5, 256, 0, stream>>>(cnt, wp, whiG, wloG);
    k_hist<<<(N_EDGES + 255) / 256, 256, 0, stream>>>(dst, cnt, epos);
    k_blocksum<<<SCAN_NB, 256, 0, stream>>>(cnt, bsum, dinv, g);
    k_scanbsum<<<1, 256, 0, stream>>>(bsum, boff);
    k_localscan<<<SCAN_NB, 256, 0, stream>>>(cnt, boff, row);

    // ---- y1 = dinv*(x@W1) + CSR fill (one kernel, two block ranges) ----
    k_transform0<<<NB_GEMM + NB_EDGE, 256, 0, stream>>>(x, dinv, whiG, wloG, yA,
                                                        src, dst, row, epos, esrc);

    // ---- 4 fused GCN layers ----
    k_layer<<<NB_GEMM, 256, 0, stream>>>(row, esrc, yA, dinv, b[0],
                                         whiG + 1 * WELEM, wloG + 1 * WELEM, yB);
    k_layer<<<NB_GEMM, 256, 0, stream>>>(row, esrc, yB, dinv, b[1],
                                         whiG + 2 * WELEM, wloG + 2 * WELEM, yA);
    k_layer<<<NB_GEMM, 256, 0, stream>>>(row, esrc, yA, dinv, b[2],
                                         whiG + 3 * WELEM, wloG + 3 * WELEM, yB);
    k_layer<<<NB_GEMM, 256, 0, stream>>>(row, esrc, yB, dinv, b[3],
                                         whiG + 4 * WELEM, wloG + 4 * WELEM, yA);

    // ---- layer 5 + fused global_add_pool ----
    k_layer_pool<<<NB_GEMM, 256, 0, stream>>>(row, esrc, yA, dinv, b[4], batch, g);

    // ---- MLP ----
    k_mlp<<<NUM_GRAPHS, FINAL_NEURON, 0, stream>>>(g, fc1W, fc1b, fc2W, fc2b, out);
}